// Round 1
// baseline (16297.276 us; speedup 1.0000x reference)
//
#include <hip/hip_runtime.h>
#include <math.h>

#define N 1024
#define W1 64
#define W2 128
#define Q 32
#define CDIM 8
#define NITER 6
#define NEWT 20
#define CHEB_M 16
#define ROUNDS 6
#define JSWEEPS 8
#define CCIT 16

// ---------------- device state (all scratch lives here, not in d_ws) ----------------
__device__ int    g_idx1[N*W1];
__device__ float  g_a0[N*W1];
__device__ float  g_u[N*W1];
__device__ float  g_unew[N*W1];
__device__ float  g_s[N*W1];
__device__ float  g_snew[N*W1];
__device__ int    g_nnz1[N];

__device__ int    g_idx2[N*W2];
__device__ float  g_w2[N*W2];     // current symmetric weights (A10 / A_new)
__device__ float  g_w2fin[N*W2];  // committed Afin
__device__ int    g_nnz2[N];
__device__ float  g_deg[N];

__device__ float  g_Sd[N*N];      // dense scratch for S_new scatter

__device__ float  g_F[N*CDIM];    // committed F
__device__ float  g_Fc[N*CDIM];   // candidate F
__device__ float  g_sn[N];

__device__ float  g_B0[N*Q];
__device__ float  g_B1[N*Q];
__device__ float  g_B2[N*Q];
__device__ float  g_B3[N*Q];

__device__ double g_G[Q*Q];
__device__ double g_RI[Q*Q];
__device__ double g_H[Q*Q];
__device__ double g_V[Q*Q];
__device__ double g_theta[Q];
__device__ int    g_perm[Q];
__device__ float  g_coef[64*4];
__device__ float  g_ab[2];        // [0]=b (upper bound), [1]=a (filter cut)
__device__ float  g_lam[1];
__device__ int    g_done[1];
__device__ int    g_cflags[2];    // [0]=commit S/u/Afin, [1]=commit F
__device__ int    g_lab[N];
__device__ int    g_lab2[N];

// ---------------- build sparse structures ----------------
__global__ void k_build1(const float* __restrict__ A) {
  int r = blockIdx.x, lane = threadIdx.x;  // 64 threads
  int cnt = 0;
  for (int c0 = 0; c0 < N; c0 += 64) {
    int j = c0 + lane;
    float v = A[r*N + j];
    bool keep = (j != r) && (v > 0.0f);
    unsigned long long m = __ballot(keep);
    int pos = __popcll(m & ((1ull << lane) - 1ull));
    if (keep) {
      int w = cnt + pos;
      if (w < W1) {
        g_idx1[r*W1 + w] = j;
        g_a0[r*W1 + w]   = v;
        g_u[r*W1 + w]    = 1.0f;
        g_s[r*W1 + w]    = 0.0f;
      }
    }
    cnt += __popcll(m);
  }
  if (lane == 0) g_nnz1[r] = cnt < W1 ? cnt : W1;
}

__global__ void k_build2(const float* __restrict__ A) {
  int r = blockIdx.x, lane = threadIdx.x;  // 64 threads
  int cnt = 0;
  for (int c0 = 0; c0 < N; c0 += 64) {
    int j = c0 + lane;
    float vr = A[r*N + j];
    float vc = A[j*N + r];
    bool keep = (j != r) && (vr > 0.0f || vc > 0.0f);
    unsigned long long m = __ballot(keep);
    int pos = __popcll(m & ((1ull << lane) - 1ull));
    if (keep) {
      int w = cnt + pos;
      if (w < W2) {
        float val = 0.5f*(vr + vc);
        g_idx2[r*W2 + w]  = j;
        g_w2[r*W2 + w]    = val;
        g_w2fin[r*W2 + w] = val;
      }
    }
    cnt += __popcll(m);
  }
  if (lane == 0) g_nnz2[r] = cnt < W2 ? cnt : W2;
}

__global__ void k_stateinit() { g_lam[0] = 0.01f; g_done[0] = 0; }

// ---------------- eigensolver pieces ----------------
__global__ void k_deg() {
  int r = blockIdx.x, lane = threadIdx.x;  // 64
  int nnz = g_nnz2[r];
  float s = 0.0f;
  for (int k = lane; k < nnz; k += 64) s += g_w2[r*W2 + k];
  for (int o = 32; o; o >>= 1) s += __shfl_xor(s, o);
  if (lane == 0) g_deg[r] = s;
}

__global__ void k_ab() {
  __shared__ float red[256];
  int t = threadIdx.x;
  float m = 0.0f;
  for (int i = t; i < N; i += 256) m = fmaxf(m, g_deg[i]);
  red[t] = m; __syncthreads();
  for (int o = 128; o; o >>= 1) { if (t < o) red[t] = fmaxf(red[t], red[t+o]); __syncthreads(); }
  if (t == 0) {
    float b = fmaxf(2.02f*red[0], 1e-3f) + 1e-6f;
    g_ab[0] = b; g_ab[1] = 0.5f*b;
  }
}

__global__ void k_xinit(float* __restrict__ X) {
  int id = blockIdx.x*256 + threadIdx.x;
  if (id >= N*Q) return;
  int i = id >> 5, q = id & 31;
  float v;
  if (q == 0) v = 0.03125f;
  else {
    unsigned h = (unsigned)(i*1664525u) + (unsigned)(q*1013904223u) + 12345u;
    h ^= h >> 16; h *= 2246822519u; h ^= h >> 13; h *= 3266489917u; h ^= h >> 16;
    v = ((float)(h & 0xFFFFFFu) / 16777216.0f) - 0.5f;
  }
  X[id] = v;
}

// project columns orthogonal to the exact null vector 1; lock col0 = const
__global__ void k_defl(float* __restrict__ Xa, float* __restrict__ Xb) {
  __shared__ float red[256];
  float* X = (blockIdx.x < Q) ? Xa : Xb;
  int c = blockIdx.x & 31;
  int t = threadIdx.x;
  float s = 0.0f;
  for (int i = t; i < N; i += 256) s += X[i*Q + c];
  red[t] = s; __syncthreads();
  for (int o = 128; o; o >>= 1) { if (t < o) red[t] += red[t+o]; __syncthreads(); }
  float mn = red[0] / (float)N;
  if (c == 0) { for (int i = t; i < N; i += 256) X[i*Q]     = 0.03125f; }
  else        { for (int i = t; i < N; i += 256) X[i*Q + c] -= mn; }
}

__global__ void k_coef() {
  double b = g_ab[0], a = g_ab[1];
  double e = 0.5*(b - a), c = 0.5*(b + a);
  double s1 = e / (0.0 - c);
  double al = s1 / e;
  g_coef[0] = (float)al; g_coef[1] = (float)(-c*al); g_coef[2] = 0.0f;
  double sp = s1;
  for (int k = 1; k < CHEB_M; k++) {
    double sn = 1.0 / (2.0/s1 - sp);
    double a2 = 2.0*sn/e;
    g_coef[k*4+0] = (float)a2;
    g_coef[k*4+1] = (float)(-c*a2);
    g_coef[k*4+2] = (float)(-sp*sn);
    sp = sn;
  }
  g_coef[63*4+0] = 1.0f; g_coef[63*4+1] = 0.0f; g_coef[63*4+2] = 0.0f;
}

// Xo = al*(L*Xc) + be*Xc + ga*Xp   (coefficients from g_coef[ci])
__global__ void k_spmm(const float* __restrict__ Xc, const float* __restrict__ Xp,
                       float* __restrict__ Xo, int ci) {
  __shared__ float part[8][Q];
  int r = blockIdx.x;
  int t = threadIdx.x;  // 256
  int col = t & 31, chunk = t >> 5;
  int nnz = g_nnz2[r];
  float acc = 0.0f;
  int k0 = chunk * 16;
  int k1 = k0 + 16; if (k1 > nnz) k1 = nnz;
  for (int k = k0; k < k1; k++) {
    int j = g_idx2[r*W2 + k];
    float w = g_w2[r*W2 + k];
    acc += w * Xc[j*Q + col];
  }
  part[chunk][col] = acc;
  __syncthreads();
  if (t < Q) {
    float s = 0.0f;
    #pragma unroll
    for (int c2 = 0; c2 < 8; c2++) s += part[c2][t];
    float xc = Xc[r*Q + t];
    float lx = g_deg[r]*xc - s;
    float al = g_coef[ci*4+0], be = g_coef[ci*4+1], ga = g_coef[ci*4+2];
    float o = al*lx + be*xc;
    if (ga != 0.0f) o += ga * Xp[r*Q + t];
    Xo[r*Q + t] = o;
  }
}

__global__ void k_gram(const float* __restrict__ Ap, const float* __restrict__ Bp,
                       double* __restrict__ Gout) {
  __shared__ double red[256];
  int ab = blockIdx.x;
  int aa = ab >> 5, bb = ab & 31;
  int t = threadIdx.x;
  double acc = 0.0;
  for (int i = t; i < N; i += 256) acc += (double)Ap[i*Q + aa] * (double)Bp[i*Q + bb];
  red[t] = acc; __syncthreads();
  for (int o = 128; o; o >>= 1) { if (t < o) red[t] += red[t+o]; __syncthreads(); }
  if (t == 0) Gout[ab] = red[0];
}

__global__ void k_cholinv() {
  __shared__ double R[Q][Q];
  __shared__ double Mi[Q][Q];
  __shared__ double fl;
  int t = threadIdx.x;  // 32
  for (int i = 0; i < Q; i++) R[i][t] = g_G[i*Q + t];
  __syncthreads();
  if (t == 0) {
    double md = 0.0;
    for (int i = 0; i < Q; i++) md = fmax(md, R[i][i]);
    fl = md*1e-13 + 1e-280;
  }
  __syncthreads();
  for (int k = 0; k < Q; k++) {
    if (t == 0) { double p = R[k][k]; if (!(p > fl)) p = fl; R[k][k] = sqrt(p); }
    __syncthreads();
    double rkk = R[k][k];
    if (t > k) R[k][t] /= rkk;
    __syncthreads();
    for (int i = k+1; i < Q; i++) {
      if (t >= i) R[i][t] -= R[k][i]*R[k][t];
    }
    __syncthreads();
  }
  {
    int j = t;
    for (int i = 0; i < Q; i++) Mi[i][j] = 0.0;
    Mi[j][j] = 1.0/R[j][j];
    for (int i = j-1; i >= 0; i--) {
      double s = 0.0;
      for (int k2 = i+1; k2 <= j; k2++) s += R[i][k2]*Mi[k2][j];
      Mi[i][j] = -s / R[i][i];
    }
  }
  __syncthreads();
  for (int i = 0; i < Q; i++) g_RI[i*Q + t] = Mi[i][t];
}

__global__ void k_smallmul(const float* __restrict__ Xin, const double* __restrict__ Mp,
                           int usePerm, float* __restrict__ Xout) {
  __shared__ float sM[Q][Q];
  __shared__ float sX[8][Q];
  int t = threadIdx.x;  // 256
  for (int id = t; id < Q*Q; id += 256) {
    int i = id >> 5, j = id & 31;
    int jj = usePerm ? g_perm[j] : j;
    sM[i][j] = (float)Mp[i*Q + jj];
  }
  int r0 = blockIdx.x * 8;
  int lr = t >> 5, col = t & 31;
  sX[lr][col] = Xin[(r0+lr)*Q + col];
  __syncthreads();
  float acc = 0.0f;
  #pragma unroll
  for (int k = 0; k < Q; k++) acc += sX[lr][k]*sM[k][col];
  Xout[(r0+lr)*Q + col] = acc;
}

__global__ void k_powa() {
  __shared__ double sH[Q][Q];
  __shared__ double v[Q], w[Q];
  __shared__ double nrm;
  int t = threadIdx.x;  // 32
  for (int i = 0; i < Q; i++) sH[i][t] = g_H[i*Q + t];
  v[t] = 1.0;
  __syncthreads();
  for (int it = 0; it < 20; it++) {
    double acc = 0.0;
    for (int k = 0; k < Q; k++) acc += sH[t][k]*v[k];
    w[t] = acc;
    __syncthreads();
    if (t == 0) {
      double nn = 0.0;
      for (int k = 0; k < Q; k++) nn += w[k]*w[k];
      nrm = sqrt(nn) + 1e-300;
    }
    __syncthreads();
    v[t] = w[t]/nrm;
    __syncthreads();
  }
  if (t == 0) {
    float b = g_ab[0];
    float a = (float)(nrm*1.1);
    if (a > 0.9f*b) a = 0.9f*b;
    if (a < 0.02f*b) a = 0.02f*b;
    g_ab[1] = a;
  }
}

__global__ void k_jacobi() {
  __shared__ double h[Q][Q], vv[Q][Q];
  __shared__ double cs[16][2];
  __shared__ int pr[16], qr[16];
  int t = threadIdx.x;  // 512
  for (int id = t; id < Q*Q; id += 512) {
    h[id>>5][id&31] = g_H[id];
    vv[id>>5][id&31] = ((id>>5) == (id&31)) ? 1.0 : 0.0;
  }
  __syncthreads();
  for (int sw = 0; sw < JSWEEPS; sw++) {
    for (int rr = 0; rr < 31; rr++) {
      if (t < 16) {
        int p, q;
        if (t == 0) { p = 31; q = rr % 31; }
        else { p = (rr + t) % 31; q = (rr + 31 - t) % 31; }
        pr[t] = p; qr[t] = q;
        double app = h[p][p], aqq = h[q][q], apq = h[p][q];
        double c, s;
        if (fabs(apq) < 1e-280) { c = 1.0; s = 0.0; }
        else {
          double ta = (aqq - app)/(2.0*apq);
          double tt = (ta >= 0.0 ? 1.0 : -1.0)/(fabs(ta) + sqrt(1.0 + ta*ta));
          c = 1.0/sqrt(1.0 + tt*tt); s = tt*c;
        }
        cs[t][0] = c; cs[t][1] = s;
      }
      __syncthreads();
      int pi = t >> 5, cj = t & 31;
      int p = pr[pi], q = qr[pi];
      double c = cs[pi][0], s = cs[pi][1];
      double hp = h[p][cj], hq = h[q][cj];
      h[p][cj] = c*hp - s*hq;
      h[q][cj] = s*hp + c*hq;
      __syncthreads();
      hp = h[cj][p]; hq = h[cj][q];
      h[cj][p] = c*hp - s*hq;
      h[cj][q] = s*hp + c*hq;
      double vp = vv[cj][p], vq = vv[cj][q];
      vv[cj][p] = c*vp - s*vq;
      vv[cj][q] = s*vp + c*vq;
      __syncthreads();
    }
  }
  if (t < Q) g_theta[t] = h[t][t];
  for (int id = t; id < Q*Q; id += 512) g_V[id] = vv[id>>5][id&31];
}

__global__ void k_sort() {
  double th[Q]; int pm[Q];
  for (int i = 0; i < Q; i++) { th[i] = g_theta[i]; pm[i] = i; }
  for (int i = 1; i < Q; i++) {
    double x = th[i]; int px = pm[i]; int j = i - 1;
    while (j >= 0 && th[j] > x) { th[j+1] = th[j]; pm[j+1] = pm[j]; j--; }
    th[j+1] = x; pm[j+1] = px;
  }
  for (int i = 0; i < Q; i++) { g_theta[i] = th[i]; g_perm[i] = pm[i]; }
}

__global__ void k_copyF(const float* __restrict__ X, float* __restrict__ Fd) {
  int id = blockIdx.x*256 + threadIdx.x;
  if (id >= N*CDIM) return;
  int i = id >> 3, j = id & 7;
  Fd[id] = X[i*Q + j];
}

// ---------------- CLR iteration pieces ----------------
__global__ void k_sn() {
  int i = blockIdx.x*256 + threadIdx.x;
  if (i >= N) return;
  float s = 0.0f;
  #pragma unroll
  for (int d = 0; d < CDIM; d++) { float v = g_F[i*CDIM + d]; s += v*v; }
  g_sn[i] = s;
}

__global__ void k_newton() {
  int r = blockIdx.x, lane = threadIdx.x;  // 64 = one wave
  int nnz = g_nnz1[r];
  bool valid = lane < nnz;
  int e = r*W1 + lane;
  int cidx = valid ? g_idx1[e] : 0;
  float a0 = valid ? g_a0[e] : 0.0f;
  float uu = valid ? g_u[e]  : 1.0f;
  float lamreg = g_lam[0];
  float fr[CDIM];
  #pragma unroll
  for (int d = 0; d < CDIM; d++) fr[d] = g_F[r*CDIM + d];
  float dot = 0.0f;
  #pragma unroll
  for (int d = 0; d < CDIM; d++) dot += fr[d]*g_F[cidx*CDIM + d];
  float dist = g_sn[r] + g_sn[cidx] - 2.0f*dot;
  dist = fmaxf(dist, 0.0f);
  float dd = uu*a0 - 0.5f*lamreg*dist;
  float tmin = valid ? (uu - dd) : 3.0e38f;
  for (int o = 32; o; o >>= 1) tmin = fminf(tmin, __shfl_xor(tmin, o));
  float lam = (tmin < 3.0e38f) ? tmin : 0.0f;
  for (int it = 0; it < NEWT; it++) {
    float v1 = (lam + dd)/uu;
    bool pos = valid && (v1 > 0.0f);
    float gg = pos ? (1.0f/uu) : 0.0f;
    float ff = pos ? v1 : 0.0f;
    for (int o = 32; o; o >>= 1) { gg += __shfl_xor(gg, o); ff += __shfl_xor(ff, o); }
    float f = ff - 1.0f;
    float step = f / (gg > 0.0f ? gg : 1.0f);
    lam = (fabsf(f) > 1e-8f) ? (lam - step) : lam;
  }
  float v1 = (lam + dd)/uu;
  float s = fmaxf(v1, 0.0f);
  if (valid) {
    g_snew[e] = s;
    float df = s - a0;
    g_unew[e] = 1.0f/(2.0f*sqrtf(df*df + 2.2204e-16f));
  }
}

__global__ void k_scatter() {
  int r = blockIdx.x, lane = threadIdx.x;  // 64
  if (lane < g_nnz1[r]) g_Sd[r*N + g_idx1[r*W1 + lane]] = g_snew[r*W1 + lane];
}

__global__ void k_gather() {
  int r = blockIdx.x, t = threadIdx.x;  // 128
  if (t < g_nnz2[r]) {
    int j = g_idx2[r*W2 + t];
    g_w2[r*W2 + t] = 0.5f*(g_Sd[r*N + j] + g_Sd[j*N + r]);
  }
}

__global__ void k_state() {
  double fn1 = 0.0;
  for (int i = 0; i < CDIM; i++) fn1 += g_theta[i];
  double fn2 = fn1 + g_theta[CDIM];
  int done = g_done[0];
  float lam = g_lam[0];
  int c1 = (fn1 > 1e-10) ? 1 : 0;
  int c2 = (!c1 && (fn2 < 1e-10)) ? 1 : 0;
  g_cflags[0] = !done;
  g_cflags[1] = (!done) && (!c2);
  if (!done) {
    if (c1) lam *= 2.0f; else if (c2) lam *= 0.5f;
    g_lam[0] = lam;
  }
  g_done[0] = done || ((!c1) && (!c2));
}

__global__ void k_commitSU() {
  if (!g_cflags[0]) return;
  int id = blockIdx.x*256 + threadIdx.x;
  if (id < N*W1) { g_s[id] = g_snew[id]; g_u[id] = g_unew[id]; }
}

__global__ void k_commitA() {
  if (!g_cflags[0]) return;
  int id = blockIdx.x*256 + threadIdx.x;
  if (id < N*W2) g_w2fin[id] = g_w2[id];
}

__global__ void k_commitF() {
  if (!g_cflags[1]) return;
  int id = blockIdx.x*256 + threadIdx.x;
  if (id < N*CDIM) g_F[id] = g_Fc[id];
}

// ---------------- connected components ----------------
__global__ void k_labinit() {
  int i = blockIdx.x*256 + threadIdx.x;
  if (i < N) g_lab[i] = i;
}

__global__ void k_ccmin() {
  int r = blockIdx.x, lane = threadIdx.x;  // 64
  int nnz = g_nnz2[r];
  int m = g_lab[r];
  for (int k = lane; k < nnz; k += 64) {
    if (g_w2fin[r*W2 + k] > 0.0f) {
      int l = g_lab[g_idx2[r*W2 + k]];
      m = l < m ? l : m;
    }
  }
  for (int o = 32; o; o >>= 1) { int l = __shfl_xor(m, o); m = l < m ? l : m; }
  if (lane == 0) g_lab2[r] = m;
}

__global__ void k_ccjump() {
  int i = blockIdx.x*256 + threadIdx.x;
  if (i < N) g_lab[i] = g_lab2[g_lab2[i]];
}

// ---------------- outputs ----------------
__global__ void k_outy(float* __restrict__ out) {
  int i = blockIdx.x*256 + threadIdx.x;
  if (i < N) out[i] = (float)g_lab[i];
}

__global__ void k_outs(float* __restrict__ out) {
  int r = blockIdx.x, lane = threadIdx.x;  // 64
  if (lane < g_nnz1[r]) out[N + r*N + g_idx1[r*W1 + lane]] = g_s[r*W1 + lane];
}

// ---------------- host orchestration ----------------
static void eig_solve(float* const* B, double* gG, double* gH, double* gRI, double* gV,
                      float* Fdst, hipStream_t stream) {
  k_deg<<<N, 64, 0, stream>>>();
  k_ab<<<1, 256, 0, stream>>>();
  k_xinit<<<N*Q/256, 256, 0, stream>>>(B[0]);
  k_defl<<<2*Q, 256, 0, stream>>>(B[0], B[1]);
  int cur = 0;
  for (int r = 0; r < ROUNDS; r++) {
    k_coef<<<1, 1, 0, stream>>>();
    int c0 = cur, c1 = (cur + 1) % 3;
    k_spmm<<<N, 256, 0, stream>>>(B[c0], B[c0], B[c1], 0);
    int prev = c0; cur = c1;
    for (int k = 1; k < CHEB_M; k++) {
      int nxt = 3 - prev - cur;
      k_spmm<<<N, 256, 0, stream>>>(B[cur], B[prev], B[nxt], k);
      prev = cur; cur = nxt;
      if (k == 4 || k == 9 || k == CHEB_M - 1)
        k_defl<<<2*Q, 256, 0, stream>>>(B[cur], B[prev]);
    }
    for (int qq = 0; qq < 2; qq++) {
      k_gram<<<Q*Q, 256, 0, stream>>>(B[cur], B[cur], gG);
      k_cholinv<<<1, 32, 0, stream>>>();
      int oth = (cur + 1) % 3;
      k_smallmul<<<N/8, 256, 0, stream>>>(B[cur], gRI, 0, B[oth]);
      cur = oth;
    }
    k_spmm<<<N, 256, 0, stream>>>(B[cur], B[cur], B[3], 63);
    k_gram<<<Q*Q, 256, 0, stream>>>(B[cur], B[3], gH);
    if (r < ROUNDS - 1) {
      k_powa<<<1, 32, 0, stream>>>();
    } else {
      k_jacobi<<<1, 512, 0, stream>>>();
      k_sort<<<1, 1, 0, stream>>>();
      int oth = (cur + 1) % 3;
      k_smallmul<<<N/8, 256, 0, stream>>>(B[cur], gV, 1, B[oth]);
      cur = oth;
      k_copyF<<<N*CDIM/256, 256, 0, stream>>>(B[cur], Fdst);
    }
  }
}

extern "C" void kernel_launch(void* const* d_in, const int* in_sizes, int n_in,
                              void* d_out, int out_size, void* d_ws, size_t ws_size,
                              hipStream_t stream) {
  const float* A = (const float*)d_in[0];
  float* out = (float*)d_out;

  void *pSd, *pG, *pH, *pRI, *pV, *pB0, *pB1, *pB2, *pB3, *pF, *pFc;
  hipGetSymbolAddress(&pSd, HIP_SYMBOL(g_Sd));
  hipGetSymbolAddress(&pG,  HIP_SYMBOL(g_G));
  hipGetSymbolAddress(&pH,  HIP_SYMBOL(g_H));
  hipGetSymbolAddress(&pRI, HIP_SYMBOL(g_RI));
  hipGetSymbolAddress(&pV,  HIP_SYMBOL(g_V));
  hipGetSymbolAddress(&pB0, HIP_SYMBOL(g_B0));
  hipGetSymbolAddress(&pB1, HIP_SYMBOL(g_B1));
  hipGetSymbolAddress(&pB2, HIP_SYMBOL(g_B2));
  hipGetSymbolAddress(&pB3, HIP_SYMBOL(g_B3));
  hipGetSymbolAddress(&pF,  HIP_SYMBOL(g_F));
  hipGetSymbolAddress(&pFc, HIP_SYMBOL(g_Fc));

  float* B[4] = {(float*)pB0, (float*)pB1, (float*)pB2, (float*)pB3};

  hipMemsetAsync(pSd, 0, sizeof(float)*(size_t)N*N, stream);
  hipMemsetAsync(d_out, 0, sizeof(float)*(size_t)out_size, stream);

  k_build1<<<N, 64, 0, stream>>>(A);
  k_build2<<<N, 64, 0, stream>>>(A);
  k_stateinit<<<1, 1, 0, stream>>>();

  // initial eigensolve on L0 -> F
  eig_solve(B, (double*)pG, (double*)pH, (double*)pRI, (double*)pV, (float*)pF, stream);

  for (int t = 0; t < NITER; t++) {
    k_sn<<<4, 256, 0, stream>>>();
    k_newton<<<N, 64, 0, stream>>>();
    k_scatter<<<N, 64, 0, stream>>>();
    k_gather<<<N, 128, 0, stream>>>();
    eig_solve(B, (double*)pG, (double*)pH, (double*)pRI, (double*)pV, (float*)pFc, stream);
    k_state<<<1, 1, 0, stream>>>();
    k_commitSU<<<N*W1/256, 256, 0, stream>>>();
    k_commitA<<<N*W2/256, 256, 0, stream>>>();
    k_commitF<<<N*CDIM/256, 256, 0, stream>>>();
  }

  k_labinit<<<4, 256, 0, stream>>>();
  for (int it = 0; it < CCIT; it++) {
    k_ccmin<<<N, 64, 0, stream>>>();
    k_ccjump<<<4, 256, 0, stream>>>();
  }
  k_outy<<<4, 256, 0, stream>>>(out);
  k_outs<<<N, 64, 0, stream>>>(out);
}